// Round 2
// baseline (7375.389 us; speedup 1.0000x reference)
//
#include <hip/hip_runtime.h>
#include <math.h>

// ---------------- path metadata (compile-time) ----------------
// INS order (i1 outer, i2 mid, io inner):
//  0:(0,0,0) 1:(0,1,1) 2:(0,2,2) 3:(1,0,1) 4:(1,1,0) 5:(1,1,2) 6:(1,2,1)
//  7:(1,3,2) 8:(2,0,2) 9:(2,1,1) 10:(2,2,0) 11:(2,2,2) 12:(2,3,1)
static constexpr int cL1[13]   = {0,0,0, 1,1,1,1,1, 2,2,2,2,2};
static constexpr int cL2[13]   = {0,1,2, 0,1,1,2,3, 0,1,2,2,3};
static constexpr int cLO[13]   = {0,1,2, 1,0,2,1,2, 2,1,0,2,1};
static constexpr int cXOFF[13] = {0,0,0, 128,128,128,128,128, 512,512,512,512,512};
static constexpr int cYOFF[13] = {0,1,4, 0,1,1,4,9, 0,1,4,4,9};
static constexpr int cCOL0[13] = {0,1,4, 1,0,4,1,4, 4,1,0,4,1};  // lo=0->0, lo=1->1, lo=2->4
static constexpr int cAOFF[13] = {0,1,4,9,18,21,36,45,60,85,100,105,130}; // cum of d1*d3 (total 145)
// sizes d1*d2*d3: 1,9,25,9,9,45,45,105,25,45,25,125,105  (total 573)
static constexpr int cCGO[13]  = {0,1,10,35,44,53,98,143,248,273,318,343,468};
// path_w: lo=0 -> sqrt(1/384), lo=1 -> sqrt(3/640), lo=2 -> sqrt(5/640)
static constexpr float cCP[13] = {
  0.05103103630798287f, 0.06846531968814576f, 0.08838834764831845f,
  0.06846531968814576f, 0.05103103630798287f, 0.08838834764831845f,
  0.06846531968814576f, 0.08838834764831845f,
  0.08838834764831845f, 0.06846531968814576f, 0.05103103630798287f,
  0.08838834764831845f, 0.06846531968814576f };

// ---------------- CG prep (exact port of reference Racah + r2c basis) ----------------
__device__ double dfact(int n) { double r = 1.0; for (int i = 2; i <= n; ++i) r *= (double)i; return r; }

__device__ double su2_cg(int j1,int m1,int j2,int m2,int j3,int m3) {
  if (m1 + m2 != m3) return 0.0;
  int vmin = max(max(-j1 + j2 + m3, -j1 + m1), 0);
  int vmax = min(min(j2 + j3 + m1, j3 - j1 + j2), j3 + m3);
  if (vmax < vmin) return 0.0;
  double C = sqrt((double)(2*j3+1) * dfact(j3+j1-j2) * dfact(j3-j1+j2) * dfact(j1+j2-j3)
                  * dfact(j3+m3) * dfact(j3-m3)
                  / (dfact(j1+j2+j3+1) * dfact(j1-m1) * dfact(j1+m1) * dfact(j2-m2) * dfact(j2+m2)));
  double S = 0.0;
  for (int v = vmin; v <= vmax; ++v) {
    double t = dfact(j2+j3+m1-v) * dfact(j1-m1+v)
             / (dfact(v) * dfact(j3-j1+j2-v) * dfact(j3+m3-v) * dfact(v+j1-j2-m3));
    int e = v + j2 + m2;            // always >= 0
    S += ((e & 1) ? -1.0 : 1.0) * t;
  }
  return C * S;
}

__device__ void q_r2c(int l, double qr[7][7], double qi[7][7]) {
  int d = 2*l + 1;
  for (int a = 0; a < 7; ++a) for (int b = 0; b < 7; ++b) { qr[a][b] = 0.0; qi[a][b] = 0.0; }
  double s = 1.0 / sqrt(2.0);
  for (int m = -l; m < 0; ++m) {
    qr[l+m][l-m] = s;       // q[l+m, l+|m|] = 1/sqrt2
    qi[l+m][l+m] = -s;      // q[l+m, l-|m|] = -i/sqrt2
  }
  qr[l][l] = 1.0;
  for (int m = 1; m <= l; ++m) {
    double sg = (m & 1) ? -1.0 : 1.0;
    qr[l+m][l+m] = sg * s;  // (-1)^m/sqrt2
    qi[l+m][l-m] = sg * s;  // i(-1)^m/sqrt2
  }
  int r = l & 3;            // multiply by (-i)^l
  if (r) for (int a = 0; a < d; ++a) for (int b = 0; b < d; ++b) {
    double re = qr[a][b], im = qi[a][b];
    if (r == 1)      { qr[a][b] =  im; qi[a][b] = -re; }
    else if (r == 2) { qr[a][b] = -re; qi[a][b] = -im; }
    else             { qr[a][b] = -im; qi[a][b] =  re; }
  }
}

__device__ void compute_w3j(int l1, int l2, int l3, float* outp) {
  int d1 = 2*l1+1, d2 = 2*l2+1, d3 = 2*l3+1;
  double C[7][7][7];
  for (int i = 0; i < d1; ++i)
    for (int k = 0; k < d2; ++k)
      for (int n = 0; n < d3; ++n)
        C[i][k][n] = su2_cg(l1, i-l1, l2, k-l2, l3, n-l3);
  double q1r[7][7], q1i[7][7], q2r[7][7], q2i[7][7], q3r[7][7], q3i[7][7];
  q_r2c(l1, q1r, q1i); q_r2c(l2, q2r, q2i); q_r2c(l3, q3r, q3i);
  double R[7][7][7];
  double nrm2 = 0.0;
  for (int j = 0; j < d1; ++j)
    for (int lx = 0; lx < d2; ++lx)
      for (int m = 0; m < d3; ++m) {
        double sr = 0.0;
        for (int i = 0; i < d1; ++i)
          for (int k = 0; k < d2; ++k)
            for (int n = 0; n < d3; ++n) {
              double c = C[i][k][n];
              if (c == 0.0) continue;
              double a = q1r[i][j],  b = q1i[i][j];
              double c2 = q2r[k][lx], d = q2i[k][lx];
              double e = q3r[n][m],  f = -q3i[n][m];     // conj(Q3[n][m])
              double re1 = a*c2 - b*d, im1 = a*d + b*c2; // Q1*Q2
              double re2 = re1*e - im1*f;                // Re((Q1*Q2)*conjQ3)
              sr += re2 * c;
            }
        R[j][lx][m] = sr;
        nrm2 += sr * sr;
      }
  double inv = 1.0 / sqrt(nrm2);
  for (int j = 0; j < d1; ++j)
    for (int lx = 0; lx < d2; ++lx)
      for (int m = 0; m < d3; ++m)
        outp[(j*d2 + lx)*d3 + m] = (float)(R[j][lx][m] * inv);
}

__global__ void cg_prep(float* __restrict__ cg) {
  int p = threadIdx.x;
  if (p < 13) compute_w3j(cL1[p], cL2[p], cLO[p], cg + cCGO[p]);
}

// ---------------- main tensor-product kernel ----------------
#define ZB 16   // nodes per workgroup

template<int P>
__device__ __forceinline__ void do_path(const float* __restrict__ x,
                                        const float* __restrict__ w,
                                        float* __restrict__ A, float* __restrict__ U,
                                        int zb, int tid, int z, int wog,
                                        float (&acc)[8][9]) {
  constexpr int d1 = 2*cL1[P] + 1;
  constexpr int d3 = 2*cLO[P] + 1;
  constexpr int us = 16*d3 + 1;     // padded LDS row stride (odd -> conflict-free)
  constexpr int c0 = cCOL0[P];
  constexpr int xoff = cXOFF[P];
  constexpr int aoff = cAOFF[P];

  // ---- U[u][z][k] = sum_i A[z][i,k] * x[z, xoff + u*d1 + i] ----
  #pragma unroll
  for (int it = 0; it < 8; ++it) {
    int idx = it*256 + tid;
    int uz = idx >> 7, uu = idx & 127;
    const float* xp = x + (size_t)(zb + uz)*1152 + xoff + uu*d1;
    const float* Ap = A + uz*145 + aoff;
    float xv[d1];
    #pragma unroll
    for (int i = 0; i < d1; ++i) xv[i] = xp[i];
    #pragma unroll
    for (int k = 0; k < d3; ++k) {
      float s = 0.f;
      #pragma unroll
      for (int i = 0; i < d1; ++i) s += Ap[i*d3 + k] * xv[i];
      U[uu*us + uz*d3 + k] = s;
    }
  }
  __syncthreads();

  // ---- acc[wo][c0+k] += W[pu][wo] * U[pu][z][k] ----
  const float* Wp = w + P*16384 + wog*8;
  #pragma unroll 2
  for (int pu = 0; pu < 128; ++pu) {
    const float4 w0 = *(const float4*)(Wp + pu*128);
    const float4 w1 = *(const float4*)(Wp + pu*128 + 4);
    float wv[8] = {w0.x, w0.y, w0.z, w0.w, w1.x, w1.y, w1.z, w1.w};
    float uv[d3];
    #pragma unroll
    for (int k = 0; k < d3; ++k) uv[k] = U[pu*us + z*d3 + k];
    #pragma unroll
    for (int wo = 0; wo < 8; ++wo)
      #pragma unroll
      for (int k = 0; k < d3; ++k)
        acc[wo][c0 + k] += wv[wo] * uv[k];
  }
  __syncthreads();
}

__global__ __launch_bounds__(256) void tp_main(const float* __restrict__ x,
                                               const float* __restrict__ y,
                                               const float* __restrict__ w,
                                               const float* __restrict__ cg,
                                               float* __restrict__ out) {
  __shared__ float A[16*145];     // per-node A_p matrices (c_p folded in)
  __shared__ float U[128*81];     // per-path U, layout [u][z*d3+k], stride 16*d3+1

  int tid = threadIdx.x;
  int zb  = blockIdx.x * ZB;

  // ---- phase A: A[z][aoff_p + i*d3 + k] = c_p * sum_j cg_p[i,j,k] y[z,j] ----
  if (tid < 208) {
    int z = tid & 15, p = tid >> 4;
    int d1 = 2*cL1[p] + 1, d2 = 2*cL2[p] + 1, d3 = 2*cLO[p] + 1;
    const float* cgp = cg + cCGO[p];
    const float* yp  = y + (size_t)(zb + z)*16 + cYOFF[p];
    float yv[7];
    for (int j = 0; j < d2; ++j) yv[j] = yp[j];
    float* Ap = A + z*145 + cAOFF[p];
    float cp = cCP[p];
    for (int i = 0; i < d1; ++i)
      for (int k = 0; k < d3; ++k) {
        float s = 0.f;
        for (int j = 0; j < d2; ++j) s += cgp[(i*d2 + j)*d3 + k] * yv[j];
        Ap[i*d3 + k] = cp * s;
      }
  }
  __syncthreads();

  float acc[8][9];
  #pragma unroll
  for (int a = 0; a < 8; ++a)
    #pragma unroll
    for (int b = 0; b < 9; ++b) acc[a][b] = 0.f;

  int z = tid & 15, wog = tid >> 4;

  do_path<0>(x, w, A, U, zb, tid, z, wog, acc);
  do_path<1>(x, w, A, U, zb, tid, z, wog, acc);
  do_path<2>(x, w, A, U, zb, tid, z, wog, acc);
  do_path<3>(x, w, A, U, zb, tid, z, wog, acc);
  do_path<4>(x, w, A, U, zb, tid, z, wog, acc);
  do_path<5>(x, w, A, U, zb, tid, z, wog, acc);
  do_path<6>(x, w, A, U, zb, tid, z, wog, acc);
  do_path<7>(x, w, A, U, zb, tid, z, wog, acc);
  do_path<8>(x, w, A, U, zb, tid, z, wog, acc);
  do_path<9>(x, w, A, U, zb, tid, z, wog, acc);
  do_path<10>(x, w, A, U, zb, tid, z, wog, acc);
  do_path<11>(x, w, A, U, zb, tid, z, wog, acc);
  do_path<12>(x, w, A, U, zb, tid, z, wog, acc);

  // ---- store: out row = [l0: 128][l1: 128*3][l2: 128*5] ----
  float* op = out + (size_t)(zb + z)*1152;
  int wo0 = wog*8;
  #pragma unroll
  for (int wo = 0; wo < 8; ++wo) {
    op[wo0 + wo] = acc[wo][0];
    #pragma unroll
    for (int k = 0; k < 3; ++k) op[128 + (wo0 + wo)*3 + k] = acc[wo][1 + k];
    #pragma unroll
    for (int k = 0; k < 5; ++k) op[512 + (wo0 + wo)*5 + k] = acc[wo][4 + k];
  }
}

// ---------------- launch ----------------
extern "C" void kernel_launch(void* const* d_in, const int* in_sizes, int n_in,
                              void* d_out, int out_size, void* d_ws, size_t ws_size,
                              hipStream_t stream) {
  const float* x = (const float*)d_in[0];
  const float* y = (const float*)d_in[1];
  const float* w = (const float*)d_in[2];
  float* out = (float*)d_out;
  float* cg  = (float*)d_ws;           // 573 floats of CG tensors

  int n = in_sizes[0] / 1152;          // 65536

  cg_prep<<<dim3(1), dim3(64), 0, stream>>>(cg);
  tp_main<<<dim3(n / ZB), dim3(256), 0, stream>>>(x, y, w, cg, out);
}